// Round 10
// baseline (122.352 us; speedup 1.0000x reference)
//
#include <hip/hip_runtime.h>
#include <cstdint>
#include <cmath>

#define NB 8192
#define ND 128
#define CAP 48
#define CAPP 49  // odd stride: epilogue bank = (rl*49+i)%32 bijective -> free
#define NEG_INF (-__builtin_inff())

typedef __attribute__((ext_vector_type(8))) __bf16 bf16x8;
typedef __attribute__((ext_vector_type(2))) __bf16 bf16x2;
typedef __attribute__((ext_vector_type(4))) float f32x4;

// ---------------------------------------------------------------------------
// Fragment-major layout AL (per dir), 16B units:
//   unit(col, kc, q, c16) = (col>>4)*256 + kc*64 + q*16 + c16   [c16 = col&15]
// holding G[col][kc*32 + q*8 + e], e=0..7. A wave's fragment load (lane l =
// q*16+c) hits units base+l -> one contiguous 1KB burst per instruction.
// (R7: 74.5->64.0 us; R9 occupancy 4 waves/SIMD: 62->45 us.)
// ---------------------------------------------------------------------------

// Insert v into ascending top-K list (identity when v <= t[0]).
__device__ __forceinline__ void insert10(float t[10], float v) {
#pragma unroll
  for (int j = 0; j < 9; ++j) t[j] = __builtin_amdgcn_fmed3f(t[j], t[j + 1], v);
  t[9] = fmaxf(t[9], v);
}
__device__ __forceinline__ void insert11(float t[11], float v) {
#pragma unroll
  for (int j = 0; j < 10; ++j) t[j] = __builtin_amdgcn_fmed3f(t[j], t[j + 1], v);
  t[10] = fmaxf(t[10], v);
}

// ---------------------------------------------------------------------------
// Row loss via column-10-only soft sort (P row-stochastic => p_neg = 1-p_pos,
// clips no-ops, both BCEs identical). Verified exact (absmax 0.0).
// ---------------------------------------------------------------------------
__device__ float row_loss(float x[11]) {
  float al[55];
#pragma unroll
  for (int layer = 0; layer < 11; ++layer) {
#pragma unroll
    for (int p = 0; p < 5; ++p) {
      int ii = (layer & 1) + 2 * p;
      float av = x[ii], bv = x[ii + 1];
      float a = atanf(bv - av) * 0.3183098861837907f + 0.5f;
      al[layer * 5 + p] = a;
      float be = 1.f - a;
      x[ii] = a * av + be * bv;
      x[ii + 1] = be * av + a * bv;
    }
  }
  float v[11];
#pragma unroll
  for (int i = 0; i < 11; ++i) v[i] = 0.f;
  v[10] = 1.f;
#pragma unroll
  for (int layer = 10; layer >= 0; --layer) {
#pragma unroll
    for (int p = 0; p < 5; ++p) {
      int ii = (layer & 1) + 2 * p;
      float a = al[layer * 5 + p];
      float be = 1.f - a;
      float va = v[ii], vb = v[ii + 1];
      v[ii] = a * va + be * vb;
      v[ii + 1] = be * va + a * vb;
    }
  }
  float C = fmaxf(logf(v[10]), -100.f);
#pragma unroll
  for (int i = 0; i < 10; ++i) C += fmaxf(logf(1.f - v[i]), -100.f);
  return C;
}

// ---------------------------------------------------------------------------
// Kernel 1: row-normalize -> bf16 (fragment-major AL layout) + fp32 pos_sims.
// Block 0 zeroes d_out. Lane l holds k=2l,2l+1 of its row; destination pair
// index = unit(row, l>>4, (l>>2)&3, row&15)*4 + (l&3).
// ---------------------------------------------------------------------------
__global__ __launch_bounds__(256, 4) void knorm(const float* __restrict__ aug1,
                                                const float* __restrict__ aug2,
                                                __bf16* __restrict__ an,
                                                float* __restrict__ pos,
                                                float* __restrict__ out) {
  if (blockIdx.x == 0 && threadIdx.x == 0) out[0] = 0.f;
  int wid = threadIdx.x >> 6;
  int l = threadIdx.x & 63;
  int row = blockIdx.x * 4 + wid;
  const float2* a1 = (const float2*)(aug1) + (size_t)row * 64;
  const float2* a2 = (const float2*)(aug2) + (size_t)row * 64;
  float2 v1 = a1[l], v2 = a2[l];
  float ss1 = v1.x * v1.x + v1.y * v1.y;
  float ss2 = v2.x * v2.x + v2.y * v2.y;
  float dp = v1.x * v2.x + v1.y * v2.y;
#pragma unroll
  for (int off = 1; off < 64; off <<= 1) {
    ss1 += __shfl_xor(ss1, off);
    ss2 += __shfl_xor(ss2, off);
    dp += __shfl_xor(dp, off);
  }
  float inv1 = 1.0f / fmaxf(sqrtf(ss1), 1e-8f);
  float inv2 = 1.0f / fmaxf(sqrtf(ss2), 1e-8f);
  bf16x2 o1, o2;
  o1[0] = (__bf16)(v1.x * inv1);
  o1[1] = (__bf16)(v1.y * inv1);
  o2[0] = (__bf16)(v2.x * inv2);
  o2[1] = (__bf16)(v2.y * inv2);
  int unit = ((row >> 4) << 8) + ((l >> 4) << 6) + (((l >> 2) & 3) << 4) + (row & 15);
  ((bf16x2*)(an))[unit * 4 + (l & 3)] = o1;
  ((bf16x2*)(an + (size_t)NB * ND))[unit * 4 + (l & 3)] = o2;
  if (l == 0) pos[row] = dp * inv1 * inv2;
}

// ---------------------------------------------------------------------------
// Kernel 2: fused Gram + self-calibrating threshold filter. R10 change:
// finish the occupancy scaling in the coalesced regime -- 8 blocks/CU =
// 8 waves/SIMD (R9's 2->4 waves/SIMD gave 1.38x; combined MfmaUtil+VALUBusy
// was still only 50%). Columns split into 8 eighths (1024 cols = 16 tiles),
// grid 2048 = 8/CU; VGPR 64 (8-wave cap) and LDS 13.3KB x 8 = 106KB both fit.
// Structure otherwise R9-exact: 64 rows/wave in regs, AL-coalesced loads,
// immediate consume, tau/CAP proof (lambda ~6.4 per row-eighth, CAP 48).
// Diagonal: self-sim (=1.0 > tau) enters cand; the diag-overlapping eighth's
// epilogue keeps top-11 and drops the max.
// ---------------------------------------------------------------------------
__global__ __launch_bounds__(256, 4) void kgram(const __bf16* __restrict__ an_all,
                                                float* __restrict__ tk,
                                                int* __restrict__ cnth,
                                                float* __restrict__ taug) {
  int dir = blockIdx.y;
  int rowg = blockIdx.x >> 3;  // 0..127 (64-row groups)
  int egt = blockIdx.x & 7;    // 0..7  (1024-col eighths)
  const bf16x8* an8 = (const bf16x8*)(an_all + (size_t)dir * NB * ND);
  int w = threadIdx.x >> 6;
  int l = threadIdx.x & 63;
  int q = l >> 4;
  int c = l & 15;
  int row_base = rowg * 64;
  const int col0 = egt * 1024;

  __shared__ float cand[64][CAPP];
  __shared__ int lcnt[64];
  __shared__ float sred[2][4];
  if (threadIdx.x < 64) lcnt[threadIdx.x] = 0;

  // Row fragments (B-operand), resident all kernel (AL: 1KB burst each).
  bf16x8 brow[4][4];
#pragma unroll
  for (int rb = 0; rb < 4; ++rb)
#pragma unroll
    for (int kc = 0; kc < 4; ++kc)
      brow[rb][kc] = an8[(size_t)row_base * 16 + rb * 256 + kc * 64 + l];

  // Column-fragment base: tile t, wave w -> units col0*16 + t*1024 + w*256 + l.
  const bf16x8* pf0 = an8 + ((size_t)col0 * 16 + w * 256 + l);
  bf16x8 a[4], a2[4];
  const f32x4 zz = {0.f, 0.f, 0.f, 0.f};
  f32x4 acc[4];

  auto loadA = [&](int t) {  // tile t -> a (4 x 1KB contiguous bursts)
    const bf16x8* p = pf0 + (size_t)(t & 15) * 1024;
#pragma unroll
    for (int kc = 0; kc < 4; ++kc) a[kc] = p[kc * 64];
  };
  auto loadA2 = [&](int t) {  // tile t -> a2
    const bf16x8* p = pf0 + (size_t)(t & 15) * 1024;
#pragma unroll
    for (int kc = 0; kc < 4; ++kc) a2[kc] = p[kc * 64];
  };
  auto mfma_tile = [&](f32x4* A, const bf16x8* src) {
#pragma unroll
    for (int rb = 0; rb < 4; ++rb)
      A[rb] = __builtin_amdgcn_mfma_f32_16x16x32_bf16(src[0], brow[rb][0], zz, 0, 0, 0);
#pragma unroll
    for (int kc = 1; kc < 4; ++kc)
#pragma unroll
      for (int rb = 0; rb < 4; ++rb)
        A[rb] = __builtin_amdgcn_mfma_f32_16x16x32_bf16(src[kc], brow[rb][kc], A[rb], 0, 0, 0);
  };
  auto consume = [&](float tau) {
#pragma unroll
    for (int rb = 0; rb < 4; ++rb) {
      int rl = rb * 16 + c;
#pragma unroll
      for (int r = 0; r < 4; ++r) {
        float v = acc[rb][r];
        if (v > tau) {
          int s = atomicAdd(&lcnt[rl], 1);
          if (s < CAP) cand[rl][s] = v;
        }
      }
    }
  };

  // ---- tile 0: compute, stats (diag-masked), tau, consume ----
  loadA(0);
  loadA2(1);
  mfma_tile(acc, a);
  loadA(2);
  bool diag0 = (row_base == col0);
  float s1 = 0.f, s2 = 0.f;
#pragma unroll
  for (int rb = 0; rb < 4; ++rb) {
#pragma unroll
    for (int r = 0; r < 4; ++r) {
      float v = acc[rb][r];
      // local col = w*16 + q*4 + r vs local row = rb*16 + c
      v = (diag0 && (w * 16 + q * 4 + r == rb * 16 + c)) ? 0.f : v;
      s1 += v;
      s2 = fmaf(v, v, s2);
    }
  }
#pragma unroll
  for (int off = 1; off < 64; off <<= 1) {
    s1 += __shfl_xor(s1, off);
    s2 += __shfl_xor(s2, off);
  }
  if (l == 0) { sred[0][w] = s1; sred[1][w] = s2; }
  __syncthreads();
  float n = diag0 ? 4032.f : 4096.f;
  float ts1 = sred[0][0] + sred[0][1] + sred[0][2] + sred[0][3];
  float ts2 = sred[1][0] + sred[1][1] + sred[1][2] + sred[1][3];
  float mu = ts1 / n;
  float sig = sqrtf(fmaxf(ts2 / n - mu * mu, 0.f));
  float tau = mu + 2.5f * sig;  // lambda ~6.4 survivors per row-eighth
  if (threadIdx.x == 0) taug[((size_t)dir * 128 + rowg) * 8 + egt] = tau;
  consume(tau);  // tile 0

  // ---- steady state: pairs (1,2),(3,4),...,(13,14), then tail tile 15 ----
  for (int t = 1; t < 15; t += 2) {
    mfma_tile(acc, a2);  // tile t (odd)
    loadA2(t + 2);
    consume(tau);
    mfma_tile(acc, a);   // tile t+1 (even)
    loadA(t + 3);        // wraps harmlessly at t=13
    consume(tau);
  }
  mfma_tile(acc, a2);    // tile 15
  consume(tau);

  // ---- epilogue: per-row top-11; drop max if eighth contains the diag ----
  __syncthreads();
  if (threadIdx.x < 64) {
    int rl = threadIdx.x;
    int cc = lcnt[rl];
    float t11[11];
#pragma unroll
    for (int j = 0; j < 11; ++j) t11[j] = NEG_INF;
    int m = cc < CAP ? cc : CAP;
    for (int i = 0; i < m; ++i) {
      float v = cand[rl][i];
      if (v > t11[0]) insert11(t11, v);
    }
    bool diagq = ((rowg >> 4) == egt);  // block rows' own cols in eighth
    int row = row_base + rl;
    float* o = tk + ((size_t)(dir * NB + row) * 8 + egt) * 10;
    if (diagq) {  // t11[10] is the self-sim (max) -> drop it
#pragma unroll
      for (int j = 0; j < 10; ++j) o[j] = t11[j];
    } else {  // keep the 10 largest
#pragma unroll
      for (int j = 0; j < 10; ++j) o[j] = t11[j + 1];
    }
    cnth[(size_t)(dir * NB + row) * 8 + egt] = cc;
  }
}

// ---------------------------------------------------------------------------
// Kernel 3: merge eighth-lists, tau-proof, soft-sort + BCE; exact brute-
// force fallback for unproven rows (statistically never fires; AL layout).
// ---------------------------------------------------------------------------
__global__ __launch_bounds__(64, 1) void ksort(const float* __restrict__ tk,
                                               const float* __restrict__ pos,
                                               const int* __restrict__ cnth,
                                               const float* __restrict__ taug,
                                               const __bf16* __restrict__ an_all,
                                               float* __restrict__ out) {
  int tid = blockIdx.x * 64 + threadIdx.x;
  int dir = tid >> 13;
  int row = tid & (NB - 1);
  int lane = threadIdx.x;

  const float* A = tk + (size_t)(dir * NB + row) * 80;
  float s10[10];
#pragma unroll
  for (int j = 0; j < 10; ++j) s10[j] = A[j];
#pragma unroll
  for (int h = 1; h < 8; ++h) {
#pragma unroll
    for (int j = 0; j < 10; ++j) {
      float v = A[h * 10 + j];
      if (v > s10[0]) insert10(s10, v);
    }
  }
  int rowg = row >> 6;
  const float* tg = taug + ((size_t)dir * 128 + rowg) * 8;
  float tmax = tg[0];
#pragma unroll
  for (int h = 1; h < 8; ++h) tmax = fmaxf(tmax, tg[h]);
  const int4* cc8 = (const int4*)cnth + (size_t)(dir * NB + row) * 2;
  int4 c0 = cc8[0], c1 = cc8[1];
  // Proof: every unreported sim is <= its eighth's tau <= tmax <= s10[0]
  // (or was dominated by 10 reported values from its eighth), and no eighth
  // overflowed CAP -> s10 is the exact top-10.
  bool ok = (c0.x <= CAP) && (c0.y <= CAP) && (c0.z <= CAP) && (c0.w <= CAP) &&
            (c1.x <= CAP) && (c1.y <= CAP) && (c1.z <= CAP) && (c1.w <= CAP) &&
            (s10[0] >= tmax);

  float C = 0.f;
  if (ok) {
    float x[11];
#pragma unroll
    for (int j = 0; j < 10; ++j) x[j] = s10[j];
    x[10] = pos[row];
    C = row_loss(x);
  }
#pragma unroll
  for (int off = 1; off < 64; off <<= 1) C += __shfl_xor(C, off);
  if (lane == 0) atomicAdd(out, C * (-1.f / (2.f * (float)NB * 11.f)));

  unsigned long long bad = __ballot(!ok);
  if (bad == 0ull) return;
  __shared__ float rv[128];
  __shared__ float lst[64][10];
  const __bf16* an = an_all + (size_t)dir * NB * ND;
  const bf16x8* an8 = (const bf16x8*)an;
  while (bad) {
    int b = __ffsll((long long)bad) - 1;
    bad &= bad - 1;
    int brow = (blockIdx.x * 64 + b) & (NB - 1);
    // rv: lane holds k=2*lane, 2*lane+1 of row brow (AL layout).
    int u = ((brow >> 4) << 8) + ((lane >> 4) << 6) + (((lane >> 2) & 3) << 4) + (brow & 15);
    bf16x2 pr = ((const bf16x2*)an)[u * 4 + (lane & 3)];
    rv[lane * 2] = (float)pr[0];
    rv[lane * 2 + 1] = (float)pr[1];
    __syncthreads();
    float t10[10];
#pragma unroll
    for (int j = 0; j < 10; ++j) t10[j] = NEG_INF;
    for (int i = 0; i < 128; ++i) {
      int col = lane + i * 64;
      if (col == brow) continue;
      float d = 0.f;
#pragma unroll
      for (int j = 0; j < 16; ++j) {  // chunk j holds k=(j>>2)*32+(j&3)*8+e
        bf16x8 p = an8[(size_t)(col >> 4) * 256 + (j >> 2) * 64 + (j & 3) * 16 + (col & 15)];
        int kb = (j >> 2) * 32 + (j & 3) * 8;
#pragma unroll
        for (int e = 0; e < 8; ++e) d = fmaf(rv[kb + e], (float)p[e], d);
      }
      if (d > t10[0]) insert10(t10, d);
    }
#pragma unroll
    for (int j = 0; j < 10; ++j) lst[lane][j] = t10[j];
    __syncthreads();
    if (lane == 0) {
      float cur[10];
#pragma unroll
      for (int j = 0; j < 10; ++j) cur[j] = lst[0][j];
      for (int s = 1; s < 64; ++s)
        for (int j = 0; j < 10; ++j) {
          float v = lst[s][j];
          if (v > cur[0]) insert10(cur, v);
        }
      float x[11];
#pragma unroll
      for (int j = 0; j < 10; ++j) x[j] = cur[j];
      x[10] = pos[brow];
      atomicAdd(out, row_loss(x) * (-1.f / (2.f * (float)NB * 11.f)));
    }
    __syncthreads();
  }
}

// ---------------------------------------------------------------------------
// ws: [an bf16 4MB][pos 32KB][tk 5.24MB][cnth 512KB][taug 8KB] ~= 9.8 MB.
// 3 nodes, no memsets: knorm zeroes d_out; cnth/taug written unconditionally.
// ---------------------------------------------------------------------------
extern "C" void kernel_launch(void* const* d_in, const int* in_sizes, int n_in,
                              void* d_out, int out_size, void* d_ws, size_t ws_size,
                              hipStream_t stream) {
  const float* aug1 = (const float*)d_in[0];
  const float* aug2 = (const float*)d_in[1];
  char* w = (char*)d_ws;
  __bf16* an = (__bf16*)w;
  float* pos = (float*)(w + (size_t)4 * 1024 * 1024);
  float* tk = pos + NB;
  int* cnth = (int*)(tk + (size_t)2 * NB * 80);
  float* taug = (float*)(cnth + (size_t)2 * NB * 8);

  knorm<<<dim3(NB / 4), dim3(256), 0, stream>>>(aug1, aug2, an, pos, (float*)d_out);
  kgram<<<dim3(1024, 2), dim3(256), 0, stream>>>(an, tk, cnth, taug);
  ksort<<<dim3(2 * NB / 64), dim3(64), 0, stream>>>(tk, pos, cnth, taug, an, (float*)d_out);
}

// Round 11
// 111.977 us; speedup vs baseline: 1.0926x; 1.0926x over previous
//
#include <hip/hip_runtime.h>
#include <cstdint>
#include <cmath>

#define NB 8192
#define ND 128
#define CAP 48
#define CAPP 49  // odd stride: epilogue bank = (rl*49+i)%32 bijective -> free
#define NEG_INF (-__builtin_inff())

typedef __attribute__((ext_vector_type(8))) __bf16 bf16x8;
typedef __attribute__((ext_vector_type(2))) __bf16 bf16x2;
typedef __attribute__((ext_vector_type(4))) float f32x4;

// ---------------------------------------------------------------------------
// Fragment-major layout AL (per dir), 16B units:
//   unit(col, kc, q, c16) = (col>>4)*256 + kc*64 + q*16 + c16   [c16 = col&15]
// holding G[col][kc*32 + q*8 + e], e=0..7. A wave's fragment load (lane l =
// q*16+c) hits units base+l -> one contiguous 1KB burst per instruction.
// (R7: 74.5->64.0 us; R9 occupancy 4 waves/SIMD: 62->45 us; R10's 8-way
// split regressed: co-residency is VGPR+AGPR-capped at ~4 waves/SIMD.)
// ---------------------------------------------------------------------------

// Insert v into ascending top-K list (identity when v <= t[0]).
__device__ __forceinline__ void insert10(float t[10], float v) {
#pragma unroll
  for (int j = 0; j < 9; ++j) t[j] = __builtin_amdgcn_fmed3f(t[j], t[j + 1], v);
  t[9] = fmaxf(t[9], v);
}
__device__ __forceinline__ void insert11(float t[11], float v) {
#pragma unroll
  for (int j = 0; j < 10; ++j) t[j] = __builtin_amdgcn_fmed3f(t[j], t[j + 1], v);
  t[10] = fmaxf(t[10], v);
}

// ---------------------------------------------------------------------------
// Row loss via column-10-only soft sort (P row-stochastic => p_neg = 1-p_pos,
// clips no-ops, both BCEs identical). Verified exact (absmax 0.0).
// ---------------------------------------------------------------------------
__device__ float row_loss(float x[11]) {
  float al[55];
#pragma unroll
  for (int layer = 0; layer < 11; ++layer) {
#pragma unroll
    for (int p = 0; p < 5; ++p) {
      int ii = (layer & 1) + 2 * p;
      float av = x[ii], bv = x[ii + 1];
      float a = atanf(bv - av) * 0.3183098861837907f + 0.5f;
      al[layer * 5 + p] = a;
      float be = 1.f - a;
      x[ii] = a * av + be * bv;
      x[ii + 1] = be * av + a * bv;
    }
  }
  float v[11];
#pragma unroll
  for (int i = 0; i < 11; ++i) v[i] = 0.f;
  v[10] = 1.f;
#pragma unroll
  for (int layer = 10; layer >= 0; --layer) {
#pragma unroll
    for (int p = 0; p < 5; ++p) {
      int ii = (layer & 1) + 2 * p;
      float a = al[layer * 5 + p];
      float be = 1.f - a;
      float va = v[ii], vb = v[ii + 1];
      v[ii] = a * va + be * vb;
      v[ii + 1] = be * va + a * vb;
    }
  }
  float C = fmaxf(logf(v[10]), -100.f);
#pragma unroll
  for (int i = 0; i < 10; ++i) C += fmaxf(logf(1.f - v[i]), -100.f);
  return C;
}

// ---------------------------------------------------------------------------
// Kernel 1: row-normalize -> bf16 (fragment-major AL layout) + fp32 pos_sims.
// Block 0 zeroes d_out. Lane l holds k=2l,2l+1 of its row; destination pair
// index = unit(row, l>>4, (l>>2)&3, row&15)*4 + (l&3).
// ---------------------------------------------------------------------------
__global__ __launch_bounds__(256, 4) void knorm(const float* __restrict__ aug1,
                                                const float* __restrict__ aug2,
                                                __bf16* __restrict__ an,
                                                float* __restrict__ pos,
                                                float* __restrict__ out) {
  if (blockIdx.x == 0 && threadIdx.x == 0) out[0] = 0.f;
  int wid = threadIdx.x >> 6;
  int l = threadIdx.x & 63;
  int row = blockIdx.x * 4 + wid;
  const float2* a1 = (const float2*)(aug1) + (size_t)row * 64;
  const float2* a2 = (const float2*)(aug2) + (size_t)row * 64;
  float2 v1 = a1[l], v2 = a2[l];
  float ss1 = v1.x * v1.x + v1.y * v1.y;
  float ss2 = v2.x * v2.x + v2.y * v2.y;
  float dp = v1.x * v2.x + v1.y * v2.y;
#pragma unroll
  for (int off = 1; off < 64; off <<= 1) {
    ss1 += __shfl_xor(ss1, off);
    ss2 += __shfl_xor(ss2, off);
    dp += __shfl_xor(dp, off);
  }
  float inv1 = 1.0f / fmaxf(sqrtf(ss1), 1e-8f);
  float inv2 = 1.0f / fmaxf(sqrtf(ss2), 1e-8f);
  bf16x2 o1, o2;
  o1[0] = (__bf16)(v1.x * inv1);
  o1[1] = (__bf16)(v1.y * inv1);
  o2[0] = (__bf16)(v2.x * inv2);
  o2[1] = (__bf16)(v2.y * inv2);
  int unit = ((row >> 4) << 8) + ((l >> 4) << 6) + (((l >> 2) & 3) << 4) + (row & 15);
  ((bf16x2*)(an))[unit * 4 + (l & 3)] = o1;
  ((bf16x2*)(an + (size_t)NB * ND))[unit * 4 + (l & 3)] = o2;
  if (l == 0) pos[row] = dp * inv1 * inv2;
}

// ---------------------------------------------------------------------------
// Kernel 2: fused Gram + self-calibrating threshold filter. R11 = R9 (proven
// best: quarters, 4 blocks/CU, AL-coalesced loads) + R0's accumulator
// double-buffer: consume(tile t-1) issues while tile t's MFMA chains are in
// flight (no dependency), filling the MFMA shadow with the filter's VALU.
// In R9 consume immediately followed its own mfma_tile -> wave stalled on
// the 4-deep dependent chain, MFMA pipe idled through consume. Register
// profile = R0's (brow 64 + 2x16 acc + 2x16 frag = 128 combined -> VGPR 64
// reported, 4 waves/SIMD preserved).
// Diagonal: self-sim (=1.0 > tau) enters cand; the diag-overlapping
// quarter's epilogue keeps top-11 and drops the max.
// ---------------------------------------------------------------------------
__global__ __launch_bounds__(256, 4) void kgram(const __bf16* __restrict__ an_all,
                                                float* __restrict__ tk,
                                                int* __restrict__ cnth,
                                                float* __restrict__ taug) {
  int dir = blockIdx.y;
  int rowg = blockIdx.x >> 2;  // 0..127 (64-row groups)
  int quar = blockIdx.x & 3;   // 0..3  (2048-col quarters)
  const bf16x8* an8 = (const bf16x8*)(an_all + (size_t)dir * NB * ND);
  int w = threadIdx.x >> 6;
  int l = threadIdx.x & 63;
  int q = l >> 4;
  int c = l & 15;
  int row_base = rowg * 64;
  const int col0 = quar * 2048;

  __shared__ float cand[64][CAPP];
  __shared__ int lcnt[64];
  __shared__ float sred[2][4];
  if (threadIdx.x < 64) lcnt[threadIdx.x] = 0;

  // Row fragments (B-operand), resident all kernel (AL: 1KB burst each).
  bf16x8 brow[4][4];
#pragma unroll
  for (int rb = 0; rb < 4; ++rb)
#pragma unroll
    for (int kc = 0; kc < 4; ++kc)
      brow[rb][kc] = an8[(size_t)row_base * 16 + rb * 256 + kc * 64 + l];

  // Column-fragment base: tile t, wave w -> units col0*16 + t*1024 + w*256 + l.
  const bf16x8* pf0 = an8 + ((size_t)col0 * 16 + w * 256 + l);
  bf16x8 a[4], a2[4];
  const f32x4 zz = {0.f, 0.f, 0.f, 0.f};
  f32x4 accA[4], accB[4];

  auto loadA = [&](int t) {  // tile t -> a (4 x 1KB contiguous bursts)
    const bf16x8* p = pf0 + (size_t)(t & 31) * 1024;
#pragma unroll
    for (int kc = 0; kc < 4; ++kc) a[kc] = p[kc * 64];
  };
  auto loadA2 = [&](int t) {  // tile t -> a2
    const bf16x8* p = pf0 + (size_t)(t & 31) * 1024;
#pragma unroll
    for (int kc = 0; kc < 4; ++kc) a2[kc] = p[kc * 64];
  };
  auto mfma_tile = [&](f32x4* A, const bf16x8* src) {
#pragma unroll
    for (int rb = 0; rb < 4; ++rb)
      A[rb] = __builtin_amdgcn_mfma_f32_16x16x32_bf16(src[0], brow[rb][0], zz, 0, 0, 0);
#pragma unroll
    for (int kc = 1; kc < 4; ++kc)
#pragma unroll
      for (int rb = 0; rb < 4; ++rb)
        A[rb] = __builtin_amdgcn_mfma_f32_16x16x32_bf16(src[kc], brow[rb][kc], A[rb], 0, 0, 0);
  };
  auto consume = [&](const f32x4* acc, float tau) {
#pragma unroll
    for (int rb = 0; rb < 4; ++rb) {
      int rl = rb * 16 + c;
#pragma unroll
      for (int r = 0; r < 4; ++r) {
        float v = acc[rb][r];
        if (v > tau) {
          int s = atomicAdd(&lcnt[rl], 1);
          if (s < CAP) cand[rl][s] = v;
        }
      }
    }
  };

  // ---- tile 0: compute, stats (diag-masked), tau, consume ----
  loadA(0);
  mfma_tile(accA, a);
  loadA2(1);
  bool diag0 = (row_base == col0);
  float s1 = 0.f, s2 = 0.f;
#pragma unroll
  for (int rb = 0; rb < 4; ++rb) {
#pragma unroll
    for (int r = 0; r < 4; ++r) {
      float v = accA[rb][r];
      // local col = w*16 + q*4 + r vs local row = rb*16 + c
      v = (diag0 && (w * 16 + q * 4 + r == rb * 16 + c)) ? 0.f : v;
      s1 += v;
      s2 = fmaf(v, v, s2);
    }
  }
#pragma unroll
  for (int off = 1; off < 64; off <<= 1) {
    s1 += __shfl_xor(s1, off);
    s2 += __shfl_xor(s2, off);
  }
  if (l == 0) { sred[0][w] = s1; sred[1][w] = s2; }
  __syncthreads();
  float n = diag0 ? 4032.f : 4096.f;
  float ts1 = sred[0][0] + sred[0][1] + sred[0][2] + sred[0][3];
  float ts2 = sred[1][0] + sred[1][1] + sred[1][2] + sred[1][3];
  float mu = ts1 / n;
  float sig = sqrtf(fmaxf(ts2 / n - mu * mu, 0.f));
  float tau = mu + 2.5f * sig;  // lambda ~12.7 survivors per row-quarter
  if (threadIdx.x == 0) taug[((size_t)dir * 128 + rowg) * 4 + quar] = tau;
  consume(accA, tau);  // tile 0

  // ---- tile 1, then pipelined pairs (2,3),(4,5),...,(30,31) ----
  mfma_tile(accA, a2);  // tile 1
  loadA(2);
  for (int t = 2; t < 32; t += 2) {
    mfma_tile(accB, a);     // tile t
    loadA2(t + 1);
    consume(accA, tau);     // tile t-1 (overlaps accB MFMAs)
    mfma_tile(accA, a2);    // tile t+1
    loadA(t + 2);           // wraps harmlessly at t=30
    consume(accB, tau);     // tile t
  }
  consume(accA, tau);       // tile 31

  // ---- epilogue: per-row top-11; drop max if quarter contains the diag ----
  __syncthreads();
  if (threadIdx.x < 64) {
    int rl = threadIdx.x;
    int cc = lcnt[rl];
    float t11[11];
#pragma unroll
    for (int j = 0; j < 11; ++j) t11[j] = NEG_INF;
    int m = cc < CAP ? cc : CAP;
    for (int i = 0; i < m; ++i) {
      float v = cand[rl][i];
      if (v > t11[0]) insert11(t11, v);
    }
    bool diagq = ((rowg >> 5) == quar);  // block rows' own cols in quarter
    int row = row_base + rl;
    float* o = tk + ((size_t)(dir * NB + row) * 4 + quar) * 10;
    if (diagq) {  // t11[10] is the self-sim (max) -> drop it
#pragma unroll
      for (int j = 0; j < 10; ++j) o[j] = t11[j];
    } else {  // keep the 10 largest
#pragma unroll
      for (int j = 0; j < 10; ++j) o[j] = t11[j + 1];
    }
    cnth[(size_t)(dir * NB + row) * 4 + quar] = cc;
  }
}

// ---------------------------------------------------------------------------
// Kernel 3: merge quarter-lists, tau-proof, soft-sort + BCE; exact brute-
// force fallback for unproven rows (statistically never fires; AL layout).
// ---------------------------------------------------------------------------
__global__ __launch_bounds__(64, 1) void ksort(const float* __restrict__ tk,
                                               const float* __restrict__ pos,
                                               const int* __restrict__ cnth,
                                               const float* __restrict__ taug,
                                               const __bf16* __restrict__ an_all,
                                               float* __restrict__ out) {
  int tid = blockIdx.x * 64 + threadIdx.x;
  int dir = tid >> 13;
  int row = tid & (NB - 1);
  int lane = threadIdx.x;

  const float* A = tk + (size_t)(dir * NB + row) * 40;
  float s10[10];
#pragma unroll
  for (int j = 0; j < 10; ++j) s10[j] = A[j];
#pragma unroll
  for (int h = 1; h < 4; ++h) {
#pragma unroll
    for (int j = 0; j < 10; ++j) {
      float v = A[h * 10 + j];
      if (v > s10[0]) insert10(s10, v);
    }
  }
  int rowg = row >> 6;
  const float* tg = taug + ((size_t)dir * 128 + rowg) * 4;
  float tmax = fmaxf(fmaxf(tg[0], tg[1]), fmaxf(tg[2], tg[3]));
  int4 cc4 = ((const int4*)cnth)[dir * NB + row];
  // Proof: every unreported sim is <= its quarter's tau <= tmax <= s10[0],
  // and no quarter overflowed CAP -> s10 is the exact top-10.
  bool ok = (cc4.x <= CAP) && (cc4.y <= CAP) && (cc4.z <= CAP) &&
            (cc4.w <= CAP) && (s10[0] >= tmax);

  float C = 0.f;
  if (ok) {
    float x[11];
#pragma unroll
    for (int j = 0; j < 10; ++j) x[j] = s10[j];
    x[10] = pos[row];
    C = row_loss(x);
  }
#pragma unroll
  for (int off = 1; off < 64; off <<= 1) C += __shfl_xor(C, off);
  if (lane == 0) atomicAdd(out, C * (-1.f / (2.f * (float)NB * 11.f)));

  unsigned long long bad = __ballot(!ok);
  if (bad == 0ull) return;
  __shared__ float rv[128];
  __shared__ float lst[64][10];
  const __bf16* an = an_all + (size_t)dir * NB * ND;
  const bf16x8* an8 = (const bf16x8*)an;
  while (bad) {
    int b = __ffsll((long long)bad) - 1;
    bad &= bad - 1;
    int brow = (blockIdx.x * 64 + b) & (NB - 1);
    // rv: lane holds k=2*lane, 2*lane+1 of row brow (AL layout).
    int u = ((brow >> 4) << 8) + ((lane >> 4) << 6) + (((lane >> 2) & 3) << 4) + (brow & 15);
    bf16x2 pr = ((const bf16x2*)an)[u * 4 + (lane & 3)];
    rv[lane * 2] = (float)pr[0];
    rv[lane * 2 + 1] = (float)pr[1];
    __syncthreads();
    float t10[10];
#pragma unroll
    for (int j = 0; j < 10; ++j) t10[j] = NEG_INF;
    for (int i = 0; i < 128; ++i) {
      int col = lane + i * 64;
      if (col == brow) continue;
      float d = 0.f;
#pragma unroll
      for (int j = 0; j < 16; ++j) {  // chunk j holds k=(j>>2)*32+(j&3)*8+e
        bf16x8 p = an8[(size_t)(col >> 4) * 256 + (j >> 2) * 64 + (j & 3) * 16 + (col & 15)];
        int kb = (j >> 2) * 32 + (j & 3) * 8;
#pragma unroll
        for (int e = 0; e < 8; ++e) d = fmaf(rv[kb + e], (float)p[e], d);
      }
      if (d > t10[0]) insert10(t10, d);
    }
#pragma unroll
    for (int j = 0; j < 10; ++j) lst[lane][j] = t10[j];
    __syncthreads();
    if (lane == 0) {
      float cur[10];
#pragma unroll
      for (int j = 0; j < 10; ++j) cur[j] = lst[0][j];
      for (int s = 1; s < 64; ++s)
        for (int j = 0; j < 10; ++j) {
          float v = lst[s][j];
          if (v > cur[0]) insert10(cur, v);
        }
      float x[11];
#pragma unroll
      for (int j = 0; j < 10; ++j) x[j] = cur[j];
      x[10] = pos[brow];
      atomicAdd(out, row_loss(x) * (-1.f / (2.f * (float)NB * 11.f)));
    }
    __syncthreads();
  }
}

// ---------------------------------------------------------------------------
// ws: [an bf16 4MB][pos 32KB][tk 2.62MB][cnth 256KB][taug 4KB] ~= 7.0 MB.
// 3 nodes, no memsets: knorm zeroes d_out; cnth/taug written unconditionally.
// ---------------------------------------------------------------------------
extern "C" void kernel_launch(void* const* d_in, const int* in_sizes, int n_in,
                              void* d_out, int out_size, void* d_ws, size_t ws_size,
                              hipStream_t stream) {
  const float* aug1 = (const float*)d_in[0];
  const float* aug2 = (const float*)d_in[1];
  char* w = (char*)d_ws;
  __bf16* an = (__bf16*)w;
  float* pos = (float*)(w + (size_t)4 * 1024 * 1024);
  float* tk = pos + NB;
  int* cnth = (int*)(tk + (size_t)2 * NB * 40);
  float* taug = (float*)(cnth + (size_t)2 * NB * 4);

  knorm<<<dim3(NB / 4), dim3(256), 0, stream>>>(aug1, aug2, an, pos, (float*)d_out);
  kgram<<<dim3(512, 2), dim3(256), 0, stream>>>(an, tk, cnth, taug);
  ksort<<<dim3(2 * NB / 64), dim3(64), 0, stream>>>(tk, pos, cnth, taug, an, (float*)d_out);
}